// Round 1
// baseline (433.847 us; speedup 1.0000x reference)
//
#include <hip/hip_runtime.h>

typedef _Float16 f16;
typedef float f32x4 __attribute__((ext_vector_type(4)));
typedef _Float16 f16x8 __attribute__((ext_vector_type(8)));
typedef _Float16 f16x4 __attribute__((ext_vector_type(4)));

#define MFMA16(a, b, c) __builtin_amdgcn_mfma_f32_16x16x32_f16((a), (b), (c), 0, 0, 0)

__device__ __forceinline__ void gld16(const void* g, void* l) {
    __builtin_amdgcn_global_load_lds((const __attribute__((address_space(1))) unsigned int*)g,
                                     (__attribute__((address_space(3))) unsigned int*)l, 16, 0, 0);
}

// ---------------- fp32 -> fp16 cast (8 elems/thread) ----------------
__global__ __launch_bounds__(256) void cvt_f32_f16(const float* __restrict__ src,
                                                   f16* __restrict__ dst, int n) {
    int i = (blockIdx.x * 256 + threadIdx.x) * 8;
    if (i >= n) return;
    float4 a = *(const float4*)(src + i);
    float4 b = *(const float4*)(src + i + 4);
    f16x8 o;
    o[0] = (f16)a.x; o[1] = (f16)a.y; o[2] = (f16)a.z; o[3] = (f16)a.w;
    o[4] = (f16)b.x; o[5] = (f16)b.y; o[6] = (f16)b.z; o[7] = (f16)b.w;
    *(f16x8*)(dst + i) = o;
}

// ---------------- GEMM: C[M,N] = A[M,K] * W[N,K]^T  (f16 in, f32 out) -------
// 128x128 tile, BK=32, 256 threads (4 waves in 2x2), m97 structure.
__global__ __launch_bounds__(256) void gemm_bt(const f16* __restrict__ A, const f16* __restrict__ W,
                                               float* __restrict__ C, int M, int N, int K) {
    __shared__ __align__(16) f16 As[128 * 32];
    __shared__ __align__(16) f16 Bs[128 * 32];
    const int tid = threadIdx.x;
    const int lane = tid & 63, wid = tid >> 6;
    const int wr = wid >> 1, wc = wid & 1;
    const int m0 = blockIdx.y * 128, n0 = blockIdx.x * 128;
    f32x4 acc[4][4] = {};

    const int off0 = wid * 1024 + lane * 16;      // byte offset in 8KB tile, issue 0
    const int off1 = off0 + 4096;                 // issue 1
    const int r0 = off0 >> 6, kc0 = (off0 & 63) >> 1;
    const int r1 = off1 >> 6, kc1 = (off1 & 63) >> 1;
    const f16* a0p = A + (size_t)(m0 + r0) * K + kc0;
    const f16* a1p = A + (size_t)(m0 + r1) * K + kc1;
    const f16* b0p = W + (size_t)(n0 + r0) * K + kc0;
    const f16* b1p = W + (size_t)(n0 + r1) * K + kc1;
    char* asb = (char*)As;
    char* bsb = (char*)Bs;

    for (int k0 = 0; k0 < K; k0 += 32) {
        gld16(a0p + k0, asb + wid * 1024);
        gld16(a1p + k0, asb + 4096 + wid * 1024);
        gld16(b0p + k0, bsb + wid * 1024);
        gld16(b1p + k0, bsb + 4096 + wid * 1024);
        __syncthreads();
        f16x8 af[4], bfr[4];
#pragma unroll
        for (int m = 0; m < 4; ++m)
            af[m] = *(const f16x8*)(asb + ((wr * 64 + m * 16 + (lane & 15)) * 32 + (lane >> 4) * 8) * 2);
#pragma unroll
        for (int n = 0; n < 4; ++n)
            bfr[n] = *(const f16x8*)(bsb + ((wc * 64 + n * 16 + (lane & 15)) * 32 + (lane >> 4) * 8) * 2);
#pragma unroll
        for (int m = 0; m < 4; ++m)
#pragma unroll
            for (int n = 0; n < 4; ++n)
                acc[m][n] = MFMA16(af[m], bfr[n], acc[m][n]);
        __syncthreads();
    }
#pragma unroll
    for (int m = 0; m < 4; ++m) {
        int row = m0 + wr * 64 + m * 16 + ((lane >> 4) << 2);
#pragma unroll
        for (int n = 0; n < 4; ++n) {
            int col = n0 + wc * 64 + n * 16 + (lane & 15);
#pragma unroll
            for (int r = 0; r < 4; ++r)
                C[(size_t)(row + r) * N + col] = acc[m][n][r];
        }
    }
}

// ---------------- RMSNorm + RoPE for q and k; one wave per (b,s,head) -------
// qkv layout: [B*S][4096] = [q(8*256) | k(4*256) | v(4*256)]
__global__ __launch_bounds__(256) void rmsrope_k(const float* __restrict__ qkv,
                                                 const float* __restrict__ cosb, const float* __restrict__ sinb,
                                                 const float* __restrict__ qnw, const float* __restrict__ knw,
                                                 f16* __restrict__ qr, f16* __restrict__ kr) {
    int wid = threadIdx.x >> 6, lane = threadIdx.x & 63;
    int task = blockIdx.x * 4 + wid;           // < B*S*12
    int slot = task % 12;
    int bs = task / 12;                        // b*2048 + s
    int b = bs >> 11, s = bs & 2047;
    const float* src;
    const float* w;
    f16* dst;
    if (slot < 8) {
        src = qkv + (size_t)bs * 4096 + slot * 256;
        w = qnw;
        dst = qr + ((size_t)(b * 8 + slot) * 2048 + s) * 256;
    } else {
        int h = slot - 8;
        src = qkv + (size_t)bs * 4096 + 2048 + h * 256;
        w = knw;
        dst = kr + ((size_t)(b * 4 + h) * 2048 + s) * 256;
    }
    int i = lane * 4;
    float4 x = *(const float4*)(src + i);
    float ss = x.x * x.x + x.y * x.y + x.z * x.z + x.w * x.w;
#pragma unroll
    for (int o = 32; o; o >>= 1) ss += __shfl_xor(ss, o, 64);
    float rs = rsqrtf(ss * (1.0f / 256.0f) + 1e-6f);
    float4 y;
    y.x = __shfl_xor(x.x, 32, 64);
    y.y = __shfl_xor(x.y, 32, 64);
    y.z = __shfl_xor(x.z, 32, 64);
    y.w = __shfl_xor(x.w, 32, 64);
    float4 wv = *(const float4*)(w + i);
    float4 wp = *(const float4*)(w + (i ^ 128));
    float4 c = *(const float4*)(cosb + (size_t)bs * 256 + i);
    float4 sn = *(const float4*)(sinb + (size_t)bs * 256 + i);
    float sgn = (lane < 32) ? -1.0f : 1.0f;
    float n0 = x.x * rs * (1.f + wv.x), n1 = x.y * rs * (1.f + wv.y);
    float n2 = x.z * rs * (1.f + wv.z), n3 = x.w * rs * (1.f + wv.w);
    float r0 = y.x * rs * (1.f + wp.x) * sgn, r1 = y.y * rs * (1.f + wp.y) * sgn;
    float r2 = y.z * rs * (1.f + wp.z) * sgn, r3 = y.w * rs * (1.f + wp.w) * sgn;
    float o0 = n0 * c.x + r0 * sn.x;
    float o1 = n1 * c.y + r1 * sn.y;
    float o2 = n2 * c.z + r2 * sn.z;
    float o3 = n3 * c.w + r3 * sn.w;
    f16x4 outv;
    outv[0] = (f16)o0; outv[1] = (f16)o1; outv[2] = (f16)o2; outv[3] = (f16)o3;
    *(f16x4*)(dst + i) = outv;
}

// ---------------- V: cast + transpose -> vt[b][kvh][d][s] (f16) -------------
__global__ __launch_bounds__(256) void vtrans_k(const float* __restrict__ qkv, f16* __restrict__ vt) {
    int g = blockIdx.x * 256 + threadIdx.x;    // total = 2*4*256*512 = 1,048,576
    int s4 = g & 511;
    int d = (g >> 9) & 255;
    int kvh = (g >> 17) & 3;
    int b = g >> 19;
    int s = s4 * 4;
    size_t src = ((size_t)(b * 2048 + s)) * 4096 + 3072 + kvh * 256 + d;
    float v0 = qkv[src];
    float v1 = qkv[src + 4096];
    float v2 = qkv[src + 2 * 4096];
    float v3 = qkv[src + 3 * 4096];
    f16x4 o;
    o[0] = (f16)v0; o[1] = (f16)v1; o[2] = (f16)v2; o[3] = (f16)v3;
    *(f16x4*)(vt + ((size_t)((b * 4 + kvh) * 256 + d) * 2048 + s)) = o;
}

// ---------------- scores: raw softcapped+masked scores into probs buffer ----
// grid (9, 32, 16): x = rel k-tile, y = q-tile, z = b*8+h
__global__ __launch_bounds__(256) void scores_k(const f16* __restrict__ qr, const f16* __restrict__ kr,
                                                float* __restrict__ probs) {
    int qt = blockIdx.y;
    int bh = blockIdx.z;
    int kt = qt - 8 + (int)blockIdx.x;
    if (kt < 0) return;
    int b = bh >> 3, h = bh & 7;
    __shared__ __align__(16) f16 Ks[64 * 256];
    int tid = threadIdx.x, lane = tid & 63, wid = tid >> 6;
    const f16* kbase = kr + ((size_t)((b * 4 + (h >> 1)) * 2048) + kt * 64) * 256;
    char* ksb = (char*)Ks;
#pragma unroll
    for (int is = 0; is < 8; ++is) {
        int off = is * 4096 + wid * 1024 + lane * 16;
        int row = off >> 9;
        int ke = (off & 511) >> 1;
        gld16(kbase + (size_t)row * 256 + ke, ksb + is * 4096 + wid * 1024);
    }
    const f16* qbase = qr + ((size_t)bh * 2048 + qt * 64) * 256;
    f16x8 af[8];
#pragma unroll
    for (int ks = 0; ks < 8; ++ks)
        af[ks] = *(const f16x8*)(qbase + (size_t)(wid * 16 + (lane & 15)) * 256 + ks * 32 + (lane >> 4) * 8);
    __syncthreads();
    f32x4 acc[4] = {};
#pragma unroll
    for (int n = 0; n < 4; ++n)
#pragma unroll
        for (int ks = 0; ks < 8; ++ks) {
            f16x8 bfr = *(const f16x8*)(ksb + ((n * 16 + (lane & 15)) * 256 + ks * 32 + (lane >> 4) * 8) * 2);
            acc[n] = MFMA16(af[ks], bfr, acc[n]);
        }
#pragma unroll
    for (int n = 0; n < 4; ++n) {
        int col = kt * 64 + n * 16 + (lane & 15);
#pragma unroll
        for (int r = 0; r < 4; ++r) {
            int row = qt * 64 + wid * 16 + ((lane >> 4) << 2) + r;
            float v = acc[n][r] * 0.0625f;      // * 256^-0.5
            v = 50.0f * tanhf(v * 0.02f);       // softcap
            bool ok = (col <= row) && ((row - col) < 512);
            probs[((size_t)bh * 2048 + row) * 2048 + col] = ok ? v : -1e9f;
        }
    }
}

// ---------------- softmax normalize in place; one wave per row --------------
__global__ __launch_bounds__(256) void softmax_k(float* __restrict__ probs) {
    int wid = threadIdx.x >> 6, lane = threadIdx.x & 63;
    int task = blockIdx.x * 4 + wid;           // < 32768
    int i = task & 2047;
    int bh = task >> 11;
    int qt = i >> 6;
    int kt0 = qt > 8 ? qt - 8 : 0;
    int col0 = kt0 * 64;
    int nt = qt - kt0 + 1;                     // <= 9
    float* row = probs + ((size_t)bh * 2048 + i) * 2048;
    float s[9];
    float m = -1e30f;
#pragma unroll
    for (int t = 0; t < 9; ++t) {
        s[t] = (t < nt) ? row[col0 + t * 64 + lane] : -1e30f;
        m = fmaxf(m, s[t]);
    }
#pragma unroll
    for (int o = 32; o; o >>= 1) m = fmaxf(m, __shfl_xor(m, o, 64));
    float sum = 0.f;
#pragma unroll
    for (int t = 0; t < 9; ++t) {
        s[t] = __expf(s[t] - m);
        sum += s[t];
    }
#pragma unroll
    for (int o = 32; o; o >>= 1) sum += __shfl_xor(sum, o, 64);
    float inv = 1.0f / sum;
#pragma unroll
    for (int t = 0; t < 9; ++t)
        if (t < nt) row[col0 + t * 64 + lane] = s[t] * inv;
}

// ---------------- PV: attn[b][s][h*256+d] = probs @ V ----------------------
// grid (32, 16): x = q-tile, y = b*8+h
__global__ __launch_bounds__(256) void pv_k(const float* __restrict__ probs, const f16* __restrict__ vt,
                                            f16* __restrict__ attn) {
    int qt = blockIdx.x, bh = blockIdx.y;
    int b = bh >> 3, h = bh & 7;
    __shared__ __align__(16) f16 Vs[256 * 64];   // [d][key]
    int tid = threadIdx.x, lane = tid & 63, wid = tid >> 6;
    int kt0 = qt > 8 ? qt - 8 : 0;
    const f16* vtb = vt + (size_t)((b * 4 + (h >> 1)) * 256) * 2048;
    char* vsb = (char*)Vs;
    f32x4 acc[16] = {};
    const float* prow0 = probs + ((size_t)bh * 2048 + qt * 64 + wid * 16 + (lane & 15)) * 2048 + (lane >> 4) * 8;
    for (int kt = kt0; kt <= qt; ++kt) {
#pragma unroll
        for (int is = 0; is < 8; ++is) {
            int off = is * 4096 + wid * 1024 + lane * 16;
            int d = off >> 7;
            int ke = (off & 127) >> 1;
            gld16(vtb + (size_t)d * 2048 + kt * 64 + ke, vsb + is * 4096 + wid * 1024);
        }
        const float* pr = prow0 + kt * 64;
        float4 xa = *(const float4*)(pr);
        float4 xb = *(const float4*)(pr + 4);
        float4 xc = *(const float4*)(pr + 32);
        float4 xd = *(const float4*)(pr + 36);
        f16x8 a0, a1;
        a0[0] = (f16)xa.x; a0[1] = (f16)xa.y; a0[2] = (f16)xa.z; a0[3] = (f16)xa.w;
        a0[4] = (f16)xb.x; a0[5] = (f16)xb.y; a0[6] = (f16)xb.z; a0[7] = (f16)xb.w;
        a1[0] = (f16)xc.x; a1[1] = (f16)xc.y; a1[2] = (f16)xc.z; a1[3] = (f16)xc.w;
        a1[4] = (f16)xd.x; a1[5] = (f16)xd.y; a1[6] = (f16)xd.z; a1[7] = (f16)xd.w;
        __syncthreads();
#pragma unroll
        for (int n = 0; n < 16; ++n) {
            f16x8 b0 = *(const f16x8*)(vsb + ((n * 16 + (lane & 15)) * 64 + (lane >> 4) * 8) * 2);
            f16x8 b1 = *(const f16x8*)(vsb + ((n * 16 + (lane & 15)) * 64 + 32 + (lane >> 4) * 8) * 2);
            acc[n] = MFMA16(a0, b0, acc[n]);
            acc[n] = MFMA16(a1, b1, acc[n]);
        }
        __syncthreads();
    }
    size_t obase = ((size_t)b * 2048 + qt * 64 + wid * 16 + ((lane >> 4) << 2)) * 2048 + h * 256;
#pragma unroll
    for (int n = 0; n < 16; ++n) {
        int col = n * 16 + (lane & 15);
#pragma unroll
        for (int r = 0; r < 4; ++r)
            attn[obase + (size_t)r * 2048 + col] = (f16)acc[n][r];
    }
}

extern "C" void kernel_launch(void* const* d_in, const int* in_sizes, int n_in,
                              void* d_out, int out_size, void* d_ws, size_t ws_size,
                              hipStream_t stream) {
    (void)in_sizes; (void)n_in; (void)out_size; (void)ws_size;
    const float* hs   = (const float*)d_in[0];
    const float* cosb = (const float*)d_in[1];
    const float* sinb = (const float*)d_in[2];
    const float* qw   = (const float*)d_in[4];
    const float* kw   = (const float*)d_in[5];
    const float* vw   = (const float*)d_in[6];
    const float* ow   = (const float*)d_in[7];
    const float* qnw  = (const float*)d_in[8];
    const float* knw  = (const float*)d_in[9];

    float* out = (float*)d_out;
    float* probs = out + (size_t)2 * 2048 * 2560;          // output 1

    char* ws = (char*)d_ws;
    f16* hsb    = (f16*)(ws);                              // 20,971,520 B
    f16* wqkv   = (f16*)(ws + 20971520);                   // 20,971,520 B
    f16* owb    = (f16*)(ws + 41943040);                   // 10,485,760 B
    float* qkvf = (float*)(ws + 52428800);                 // 67,108,864 B
    f16* qr     = (f16*)(ws + 119537664);                  // 16,777,216 B
    f16* kr     = (f16*)(ws + 136314880);                  //  8,388,608 B
    f16* vt     = (f16*)(ws + 144703488);                  //  8,388,608 B
    f16* attn   = (f16*)(ws + 153092096);                  // 16,777,216 B -> total 169,869,312 B

    // fp32 -> fp16 casts
    cvt_f32_f16<<<5120, 256, 0, stream>>>(hs, hsb, 10485760);
    cvt_f32_f16<<<2560, 256, 0, stream>>>(qw, wqkv, 5242880);
    cvt_f32_f16<<<1280, 256, 0, stream>>>(kw, wqkv + 5242880, 2621440);
    cvt_f32_f16<<<1280, 256, 0, stream>>>(vw, wqkv + 7864320, 2621440);
    cvt_f32_f16<<<2560, 256, 0, stream>>>(ow, owb, 5242880);

    // fused QKV projection: [4096, 2560] x [4096, 2560]^T -> [4096, 4096] fp32
    gemm_bt<<<dim3(32, 32), 256, 0, stream>>>(hsb, wqkv, qkvf, 4096, 4096, 2560);

    // RMSNorm + RoPE -> qr [B,H,S,256], kr [B,KVH,S,256]; V transpose -> vt [B,KVH,256,S]
    rmsrope_k<<<12288, 256, 0, stream>>>(qkvf, cosb, sinb, qnw, knw, qr, kr);
    vtrans_k<<<4096, 256, 0, stream>>>(qkvf, vt);

    // probs: zero everything (masked region), then scores + softmax in window band
    hipMemsetAsync(probs, 0, (size_t)268435456, stream);
    scores_k<<<dim3(9, 32, 16), 256, 0, stream>>>(qr, kr, probs);
    softmax_k<<<8192, 256, 0, stream>>>(probs);

    // PV -> attn [B,S,H*256] f16
    pv_k<<<dim3(32, 16), 256, 0, stream>>>(probs, vt, attn);

    // O projection: [4096, 2048] x [2560, 2048]^T -> [4096, 2560] fp32 (output 0)
    gemm_bt<<<dim3(20, 32), 256, 0, stream>>>(attn, owb, out, 4096, 2560, 2048);
}